// Round 4
// baseline (40.617 us; speedup 1.0000x reference)
//
#include <hip/hip_runtime.h>

constexpr int C = 26;                       // floats per cell
constexpr int TILE_ROWS = 128;              // rows per tile
constexpr int THREADS = 256;
constexpr int GRID = 768;                   // 3 blocks/CU * 256 CU, persistent
constexpr int TILE_FLOATS = TILE_ROWS * C;  // 3328 floats = 13312 B per input
constexpr float LAMBDA_LOC = 10.0f;
constexpr float LAMBDA_NOOBJ = 0.5f;

__device__ __forceinline__ void stage16(const float* g, float* lds_uniform) {
    // width-16 global->LDS: per-lane global src, wave-uniform LDS dst (+ HW lane*16)
    __builtin_amdgcn_global_load_lds(
        (const __attribute__((address_space(1))) unsigned int*)g,
        (__attribute__((address_space(3))) unsigned int*)lds_uniform,
        16, 0, 0);
}

// Stage one tile (both inputs) into LDS. 832 float4-chunks per input:
// k=0..2 full-block (768), tail 64 chunks by wave 0. Wave-aligned, no divergence.
__device__ __forceinline__ void stage_tile(const float* gp, const float* gt,
                                           float* lp, float* lt, int tid, int wid) {
    #pragma unroll
    for (int k = 0; k < 3; ++k) {
        int j = k * 256 + tid;                 // float4 index within tile
        int u = (k * 256 + wid * 64) * 4;      // wave-uniform LDS float offset
        stage16(gp + j * 4, lp + u);
        stage16(gt + j * 4, lt + u);
    }
    if (wid == 0) {                            // chunks [768,832)
        int j = 768 + tid;                     // tid in [0,64)
        stage16(gp + j * 4, lp + 768 * 4);
        stage16(gt + j * 4, lt + 768 * 4);
    }
}

__device__ __forceinline__ float iou_f(float b1x, float b1y, float b1w, float b1h,
                                       float b2x, float b2y, float b2w, float b2h) {
    float cx1 = b1x * 64.f, cy1 = b1y * 64.f, hw1 = b1w * 224.f, hh1 = b1h * 224.f;
    float l1 = cx1 - hw1, t1 = cy1 - hh1, r1 = cx1 + hw1, bo1 = cy1 + hh1;
    float cx2 = b2x * 64.f, cy2 = b2y * 64.f, hw2 = b2w * 224.f, hh2 = b2h * 224.f;
    float l2 = cx2 - hw2, t2 = cy2 - hh2, r2 = cx2 + hw2, bo2 = cy2 + hh2;
    float xA = fmaxf(l1, l2), yA = fmaxf(t1, t2);
    float xB = fminf(r1, r2), yB = fminf(bo1, bo2);
    float iw = fmaxf(0.f, xB - xA + 1.f);
    float ih = fmaxf(0.f, yB - yA + 1.f);
    float inter = iw * ih;
    float a1 = (r1 - l1 + 1.f) * (bo1 - t1 + 1.f);
    float a2 = (r2 - l2 + 1.f) * (bo2 - t2 + 1.f);
    return inter / (a1 + a2 - inter);
}

__device__ __forceinline__ float row_loss(const float* lds_p, const float* lds_t, int row) {
    const float2* pr = reinterpret_cast<const float2*>(lds_p + row * C);
    const float2* tr = reinterpret_cast<const float2*>(lds_t + row * C);

    float2 p01 = pr[0], p23 = pr[1], p45 = pr[2], p67 = pr[3], p89 = pr[4];
    float2 t01 = tr[0], t23 = tr[1], t45 = tr[2], t67 = tr[3], t89 = tr[4];

    float cls = 0.f;
    #pragma unroll
    for (int j = 5; j < 13; ++j) {
        float2 a = pr[j], b = tr[j];
        float dx = a.x - b.x, dy = a.y - b.y;
        cls = fmaf(dx, dx, cls);
        cls = fmaf(dy, dy, cls);
    }

    float obj   = t45.x;
    float noobj = 1.f - obj;

    float iou1 = iou_f(p01.x, p01.y, p23.x, p23.y, t01.x, t01.y, t23.x, t23.y);
    float iou2 = iou_f(p45.y, p67.x, p67.y, p89.x, t01.x, t01.y, t23.x, t23.y);

    bool  best2 = iou2 > iou1;
    float iou_m = best2 ? iou2 : iou1;

    float vpx = best2 ? p45.y : p01.x;
    float vpy = best2 ? p67.x : p01.y;
    float vpw = best2 ? p67.y : p23.x;
    float vph = best2 ? p89.x : p23.y;
    float vpc = best2 ? p89.y : p45.x;
    float vtx = best2 ? t45.y : t01.x;
    float vty = best2 ? t67.x : t01.y;
    float vtw = best2 ? t67.y : t23.x;
    float vth = best2 ? t89.x : t23.y;

    float dx = vpx - vtx, dy = vpy - vty;
    float xy = dx * dx + dy * dy;
    float sw = sqrtf(vpw) - sqrtf(vtw);
    float sh = sqrtf(vph) - sqrtf(vth);
    float wh = sw * sw + sh * sh;
    float dc = vpc - iou_m;
    float oc = dc * dc;
    float d1 = p45.x - t45.x;
    float d2 = p89.y - t89.y;

    return obj * (LAMBDA_LOC * (xy + wh) + oc + 2.f * cls)
         + LAMBDA_NOOBJ * noobj * (d1 * d1 + d2 * d2);
}

// Persistent blocks, double-buffered LDS pipeline: stage(t+1) -> compute(t) -> barrier.
// rows must be a multiple of TILE_ROWS (802816 = 6272*128).
__global__ __launch_bounds__(THREADS, 3) void yolo_main(
    const float* __restrict__ pred, const float* __restrict__ targ,
    float* __restrict__ out, int nTiles)
{
    __shared__ float lp[2][TILE_FLOATS];
    __shared__ float lt[2][TILE_FLOATS];

    const int tid = threadIdx.x;
    const int wid = tid >> 6;
    float acc = 0.f;

    int t = blockIdx.x;
    if (t < nTiles)
        stage_tile(pred + (size_t)t * TILE_FLOATS, targ + (size_t)t * TILE_FLOATS,
                   lp[0], lt[0], tid, wid);
    __syncthreads();                       // buf0 ready (vmcnt drain)

    int cur = 0;
    for (; t < nTiles; t += GRID) {
        int tn = t + GRID;
        if (tn < nTiles)                   // issue next tile's loads FIRST
            stage_tile(pred + (size_t)tn * TILE_FLOATS, targ + (size_t)tn * TILE_FLOATS,
                       lp[cur ^ 1], lt[cur ^ 1], tid, wid);
        if (tid < TILE_ROWS)               // compute current tile (hides load latency)
            acc += row_loss(lp[cur], lt[cur], tid);
        __syncthreads();                   // drains vmcnt: buf^1 ready; readers of buf done
        cur ^= 1;
    }

    // ---- one block reduce at the end ----
    #pragma unroll
    for (int off = 32; off > 0; off >>= 1)
        acc += __shfl_down(acc, off);

    __shared__ float wsum[THREADS / 64];
    if ((tid & 63) == 0) wsum[wid] = acc;
    __syncthreads();
    if (tid == 0)
        atomicAdd(out, wsum[0] + wsum[1] + wsum[2] + wsum[3]);
}

extern "C" void kernel_launch(void* const* d_in, const int* in_sizes, int n_in,
                              void* d_out, int out_size, void* d_ws, size_t ws_size,
                              hipStream_t stream) {
    const float* pred = (const float*)d_in[0];
    const float* targ = (const float*)d_in[1];
    float* out = (float*)d_out;
    int rows = in_sizes[0] / C;             // 802816
    int nTiles = rows / TILE_ROWS;          // 6272 (exact)

    hipMemsetAsync(out, 0, sizeof(float), stream);   // zero accumulator (capture-safe)
    yolo_main<<<GRID, THREADS, 0, stream>>>(pred, targ, out, nTiles);
}